// Round 2
// 816.205 us; speedup vs baseline: 1.1719x; 1.1719x over previous
//
#include <hip/hip_runtime.h>
#include <cstdint>
#include <cstddef>

// HiPPO x_{k+1} = Ab x_k + b u_k, f[k]=x_{k+1}, L=65536, N=512.
// Chunked scan (C=16, G=4096): one big GEMM F(4096x8192)=Xcat(4096x544)@Wcat,
// chunk states via Blelloch sweep with on-device matrix powers.
// Numerics: split-f16 (Ootomo), fp32 accumulate -> ~22-bit mantissa.
// R6 (= R5 resubmit after infra failure; design audited for deadlock, none
// found): gemm_main as 256x256-tile / BK=32 / 8-wave double-buffered
// phase-interleaved schedule (HK 8-phase template adapted to 4 operand
// streams), vmcnt drained once per K-step, setprio around MFMA, XCD-aware
// 8x8-rectangle swizzle (bijective). Low-half split stored as RAW residual
// (v-h) so cross terms accumulate into ONE fp32 acc (halves acc VGPRs).
// Workspace ~46 MB (stay under 53 MB).

typedef _Float16 half_t;
typedef _Float16 f16x8 __attribute__((ext_vector_type(8)));
typedef float f32x4 __attribute__((ext_vector_type(4)));

static constexpr int KPAD = 544;               // 512 + 16 u-taps + 16 pad
static constexpr size_t MSZ = (size_t)512 * 512;
static constexpr float INV2048 = 1.f / 2048.f;

__device__ inline void split1(float v, half_t& h, half_t& l) {
  h = (half_t)v;
  l = (half_t)((v - (float)h) * 2048.f);
}
// residual split: l is the true residual (no 2048 scale); consumer (gemm_main)
// accumulates h*l' + l*h' directly into the same fp32 accumulator.
__device__ inline void split1r(float v, half_t& h, half_t& l) {
  h = (half_t)v;
  l = (half_t)(v - (float)h);
}

// ---------------- utility kernels ----------------

__global__ void zero_kernel(float4* __restrict__ p, int n4) {
  int i = blockIdx.x * 256 + threadIdx.x;
  if (i < n4) p[i] = make_float4(0.f, 0.f, 0.f, 0.f);
}

__global__ void copy_ab_kernel(const float* __restrict__ Ab, float* __restrict__ V0) {
  int idx = blockIdx.x * 256 + threadIdx.x;    // 262144
  V0[idx] = Ab[idx];
}

__global__ void cast_x0_kernel(const float* __restrict__ x0, half_t* __restrict__ xh) {
  xh[threadIdx.x] = (half_t)x0[threadIdx.x];
}

// K[t,n] = (Ab^t b)[n], t=0..15. One wave per (t,n): coalesced m-stride + reduce.
__global__ void kbuild_kernel(const float* __restrict__ V, const float* __restrict__ b,
                              float* __restrict__ K) {
  int gw = blockIdx.x * 4 + (threadIdx.x >> 6);   // 0..8191
  int lane = threadIdx.x & 63;
  int t = gw >> 9, n = gw & 511;
  if (t == 0) { if (lane == 0) K[n] = b[n]; return; }
  const float* row = V + (size_t)(t - 1) * MSZ + (size_t)n * 512;
  float acc = 0.f;
#pragma unroll
  for (int m = 0; m < 512; m += 64) acc += row[m + lane] * b[m + lane];
#pragma unroll
  for (int s = 32; s; s >>= 1) acc += __shfl_down(acc, s, 64);
  if (lane == 0) K[t * 512 + n] = acc;
}

// WcatT[(i*512+n), k]: k<512 -> Ab^{i+1}[n,k]; 512+j -> (j<=i)?K[i-j,n]:0; pad 0
__global__ void wcat_fill_kernel(const float* __restrict__ V, const float* __restrict__ K,
                                 half_t* __restrict__ Wh, half_t* __restrict__ Wl) {
  size_t idx = (size_t)blockIdx.x * 256 + threadIdx.x;
  if (idx >= (size_t)8192 * KPAD) return;
  int row = (int)(idx / KPAD), k = (int)(idx % KPAD);
  int i = row >> 9, n = row & 511;
  float v = 0.f;
  if (k < 512) v = V[(size_t)i * MSZ + (size_t)n * 512 + k];
  else if (k < 528) { int j = k - 512; if (j <= i) v = K[(i - j) * 512 + n]; }
  half_t h, l; split1r(v, h, l);
  Wh[idx] = h; Wl[idx] = l;
}

// Z0[c,n] = sum_{j<16} K[15-j,n] * u[16c+j]   (plain f16 out)
__global__ void leaf_kernel(const float* __restrict__ u, const float* __restrict__ K,
                            half_t* __restrict__ Z) {
  __shared__ float us[16];
  int c = blockIdx.x, n = threadIdx.x;
  if (n < 16) us[n] = u[c * 16 + n];
  __syncthreads();
  float acc = 0.f;
#pragma unroll
  for (int j = 0; j < 16; ++j) acc += K[(15 - j) * 512 + n] * us[j];
  Z[(size_t)c * 512 + n] = (half_t)acc;
}

// Xcat cols [512,544): u chunk (16 taps) + zero pad (16), split pair
__global__ void xtail_kernel(const float* __restrict__ u,
                             half_t* __restrict__ Xh, half_t* __restrict__ Xl) {
  int idx = blockIdx.x * 256 + threadIdx.x;    // 4096*32
  int c = idx >> 5, j = idx & 31;
  float v = (j < 16) ? u[c * 16 + j] : 0.f;
  size_t o = (size_t)c * KPAD + 512 + j;
  half_t h, l; split1r(v, h, l);
  Xh[o] = h; Xl[o] = l;
}

// -------- chain GEMM: C += A(512x512 fp32) @ B(512x512 fp32) -----------------
// split-on-the-fly, fragment-native LDS, split-K=4 via grid.z, fp32 atomicAdd.
// grid (8, 8, 4*batch); z = b*4 + kslice. C must be pre-zeroed.
__global__ __launch_bounds__(256)
void gemm_nn512(const float* __restrict__ A, long sA,
                const float* __restrict__ B, long sB,
                float* __restrict__ C, long sC) {
  __shared__ __align__(16) half_t Ash[64 * 32];
  __shared__ __align__(16) half_t Asl[64 * 32];
  __shared__ __align__(16) half_t Bsh[64 * 32];
  __shared__ __align__(16) half_t Bsl[64 * 32];
  int bz = blockIdx.z, bb = bz >> 2, sl = bz & 3;
  A += (size_t)bb * sA; B += (size_t)bb * sB; C += (size_t)bb * sC;
  int m0 = blockIdx.x * 64, n0 = blockIdx.y * 64;
  int tid = threadIdx.x, wave = tid >> 6, lane = tid & 63;
  int wm = (wave & 1) * 32, wn = (wave >> 1) * 32;
  f32x4 acc[2][2], accc[2][2];
  for (int i = 0; i < 2; ++i)
    for (int j = 0; j < 2; ++j) {
      acc[i][j] = (f32x4){0.f, 0.f, 0.f, 0.f};
      accc[i][j] = (f32x4){0.f, 0.f, 0.f, 0.f};
    }
  int rb = tid >> 6, mm = tid & 15, kseg = (tid >> 4) & 3;
  for (int kt = sl * 4; kt < sl * 4 + 4; ++kt) {
    int k0 = kt * 32;
    {  // A: row-major fp32, fragment gather -> linear LDS (tid*16B)
      const float* ap = A + (size_t)(m0 + rb * 16 + mm) * 512 + k0 + kseg * 8;
      f16x8 hv, lv;
#pragma unroll
      for (int j = 0; j < 8; ++j) { half_t h, l; split1(ap[j], h, l); hv[j] = h; lv[j] = l; }
      *(f16x8*)(Ash + tid * 8) = hv;
      *(f16x8*)(Asl + tid * 8) = lv;
    }
    {  // B: column gather (transpose), fragment order
      f16x8 hv, lv;
#pragma unroll
      for (int j = 0; j < 8; ++j) {
        float v = B[(size_t)(k0 + kseg * 8 + j) * 512 + n0 + rb * 16 + mm];
        half_t h, l; split1(v, h, l); hv[j] = h; lv[j] = l;
      }
      *(f16x8*)(Bsh + tid * 8) = hv;
      *(f16x8*)(Bsl + tid * 8) = lv;
    }
    __syncthreads();
    f16x8 afh[2], afl[2], bfh[2], bfl[2];
#pragma unroll
    for (int i = 0; i < 2; ++i) {
      int ra = (wm >> 4) + i, rbn = (wn >> 4) + i;
      afh[i] = *(const f16x8*)(Ash + ra * 512 + lane * 8);
      afl[i] = *(const f16x8*)(Asl + ra * 512 + lane * 8);
      bfh[i] = *(const f16x8*)(Bsh + rbn * 512 + lane * 8);
      bfl[i] = *(const f16x8*)(Bsl + rbn * 512 + lane * 8);
    }
#pragma unroll
    for (int i = 0; i < 2; ++i)
#pragma unroll
      for (int j = 0; j < 2; ++j) {
        acc[i][j] = __builtin_amdgcn_mfma_f32_16x16x32_f16(afh[i], bfh[j], acc[i][j], 0, 0, 0);
        accc[i][j] = __builtin_amdgcn_mfma_f32_16x16x32_f16(afh[i], bfl[j], accc[i][j], 0, 0, 0);
        accc[i][j] = __builtin_amdgcn_mfma_f32_16x16x32_f16(afl[i], bfh[j], accc[i][j], 0, 0, 0);
      }
    __syncthreads();
  }
  int ml = lane & 15, quad = lane >> 4;
  for (int i = 0; i < 2; ++i)
    for (int j = 0; j < 2; ++j)
      for (int rr = 0; rr < 4; ++rr) {
        int gm = m0 + wm + i * 16 + quad * 4 + rr;
        int gn = n0 + wn + j * 16 + ml;
        atomicAdd(&C[(size_t)gm * 512 + gn], acc[i][j][rr] + accc[i][j][rr] * INV2048);
      }
}

// -------- sweep GEMM: C(Mx512) = A(Mx512 f16) @ S^T + D; S fp32 row-major ----
// 2 mfma (A plain f16, S split). Fused even-row copy (down-sweep rowcopy).
__global__ __launch_bounds__(256)
void gemm_nt_sweep(const half_t* __restrict__ A, long ldA,
                   const float* __restrict__ BT,
                   const half_t* __restrict__ D, long ldD,
                   half_t* __restrict__ Ch, half_t* __restrict__ Cl,
                   long ldC, int rScale, int rOff, int doCopy, int M) {
  __shared__ __align__(16) half_t Ash[64 * 32];
  __shared__ __align__(16) half_t Bsh[64 * 32];
  __shared__ __align__(16) half_t Bsl[64 * 32];
  int m0 = blockIdx.x * 64, n0 = blockIdx.y * 64;
  int tid = threadIdx.x, wave = tid >> 6, lane = tid & 63;
  int wm = (wave & 1) * 32, wn = (wave >> 1) * 32;
  f32x4 acc[2][2], accc[2][2];
  for (int i = 0; i < 2; ++i)
    for (int j = 0; j < 2; ++j) {
      acc[i][j] = (f32x4){0.f, 0.f, 0.f, 0.f};
      accc[i][j] = (f32x4){0.f, 0.f, 0.f, 0.f};
    }
  int rb = tid >> 6, mm = tid & 15, kseg = (tid >> 4) & 3;
  for (int kt = 0; kt < 16; ++kt) {
    int k0 = kt * 32;
    int arow = m0 + rb * 16 + mm;
    f16x8 av = (f16x8){0, 0, 0, 0, 0, 0, 0, 0};
    if (arow < M) av = *(const f16x8*)(A + (size_t)arow * ldA + k0 + kseg * 8);
    *(f16x8*)(Ash + tid * 8) = av;
    // fused even-row copy: out[2*arow, k0+kseg*8 ..] = A values (down-sweep)
    if (doCopy && k0 >= n0 && k0 < n0 + 64 && arow < M) {
      size_t co = (size_t)(2 * arow) * ldC + k0 + kseg * 8;
      *(f16x8*)(Ch + co) = av;
      if (Cl) *(f16x8*)(Cl + co) = (f16x8){0, 0, 0, 0, 0, 0, 0, 0};
    }
    {  // S row gather (fp32) -> split fragment
      const float* bp = BT + (size_t)(n0 + rb * 16 + mm) * 512 + k0 + kseg * 8;
      f16x8 hv, lv;
#pragma unroll
      for (int j = 0; j < 8; ++j) { half_t h, l; split1(bp[j], h, l); hv[j] = h; lv[j] = l; }
      *(f16x8*)(Bsh + tid * 8) = hv;
      *(f16x8*)(Bsl + tid * 8) = lv;
    }
    __syncthreads();
    f16x8 af[2], bfh[2], bfl[2];
#pragma unroll
    for (int i = 0; i < 2; ++i) {
      af[i] = *(const f16x8*)(Ash + ((wm >> 4) + i) * 512 + lane * 8);
      bfh[i] = *(const f16x8*)(Bsh + ((wn >> 4) + i) * 512 + lane * 8);
      bfl[i] = *(const f16x8*)(Bsl + ((wn >> 4) + i) * 512 + lane * 8);
    }
#pragma unroll
    for (int i = 0; i < 2; ++i)
#pragma unroll
      for (int j = 0; j < 2; ++j) {
        acc[i][j] = __builtin_amdgcn_mfma_f32_16x16x32_f16(af[i], bfh[j], acc[i][j], 0, 0, 0);
        accc[i][j] = __builtin_amdgcn_mfma_f32_16x16x32_f16(af[i], bfl[j], accc[i][j], 0, 0, 0);
      }
    __syncthreads();
  }
  int ml = lane & 15, quad = lane >> 4;
  for (int i = 0; i < 2; ++i)
    for (int j = 0; j < 2; ++j)
      for (int rr = 0; rr < 4; ++rr) {
        int gm = m0 + wm + i * 16 + quad * 4 + rr;
        int gn = n0 + wn + j * 16 + ml;
        if (gm >= M) continue;
        float v = acc[i][j][rr] + accc[i][j][rr] * INV2048;
        if (D) v += (float)D[(size_t)gm * ldD + gn];
        size_t co = ((size_t)gm * rScale + rOff) * ldC + gn;
        if (Cl) { half_t h, l; split1r(v, h, l); Ch[co] = h; Cl[co] = l; }
        else Ch[co] = (half_t)v;
      }
}

// -------- main GEMM: 4096 x 8192 x 544 --------------------------------------
__device__ inline void load_lds16(const half_t* g, half_t* l) {
  __builtin_amdgcn_global_load_lds(
      (const __attribute__((address_space(1))) uint32_t*)g,
      (__attribute__((address_space(3))) uint32_t*)l, 16, 0, 0);
}

// 256x256 tile, BK=32 (17 steps), 8 waves (2Mx4N), wave tile 128x64.
// LDS: 2 buffers x 4 streams (Ah,Al,Bh,Bl) x 256x32 f16 = 128 KiB, dbuf.
// Schedule per K-step: 3 phases {ds_read || stage-next -> bar -> lgkm ->
// setprio MFMA setprio -> bar}; vmcnt drained ONCE per step at the end
// (loads issued in phases A/B have ~2 phases of slack). Low split is raw
// residual -> single fp32 accumulator (128 acc VGPRs).
__global__ __launch_bounds__(512, 2)
void gemm_main(const half_t* __restrict__ Ah, const half_t* __restrict__ Al,
               const half_t* __restrict__ Bh, const half_t* __restrict__ Bl,
               float* __restrict__ C) {
  __shared__ __align__(16) half_t sm[2 * 4 * 8192];   // 128 KiB
  // XCD swizzle: 512 blocks; xcd = bid&7 owns an 8x8 tile rectangle
  int bid = blockIdx.x;
  int xcd = bid & 7, loc = bid >> 3;                  // loc 0..63
  int mt = (xcd & 1) * 8 + (loc >> 3);                // 0..15
  int nt = (xcd >> 1) * 8 + (loc & 7);                // 0..31
  int m0 = mt * 256, n0 = nt * 256;
  int tid = threadIdx.x, wave = tid >> 6, lane = tid & 63;
  int wm = (wave & 1) * 128, wn = (wave >> 1) * 64;
  int mm = lane & 15, kseg = lane >> 4;
  f32x4 acc[8][4];
#pragma unroll
  for (int f = 0; f < 8; ++f)
#pragma unroll
    for (int g = 0; g < 4; ++g) acc[f][g] = (f32x4){0.f, 0.f, 0.f, 0.f};

  // staging: row-block rb = wave + 8q, row = rb*16 + mm, col = kseg*8
  const size_t ga0 = (size_t)(m0 + wave * 16 + mm) * KPAD + kseg * 8;
  const size_t gb0 = (size_t)(n0 + wave * 16 + mm) * KPAD + kseg * 8;
  const size_t qstep = (size_t)128 * KPAD;            // q=1: +128 rows

  auto stage = [&](int nb, int kt, int q) {
    size_t go = (size_t)kt * 32 + (size_t)q * qstep;
    half_t* d = sm + (size_t)nb * 32768 + (size_t)(wave + 8 * q) * 512;
    load_lds16(Ah + ga0 + go, d);
    load_lds16(Al + ga0 + go, d + 8192);
    load_lds16(Bh + gb0 + go, d + 16384);
    load_lds16(Bl + gb0 + go, d + 24576);
  };

  stage(0, 0, 0);
  stage(0, 0, 1);
  asm volatile("s_waitcnt vmcnt(0)" ::: "memory");
  __builtin_amdgcn_s_barrier();

  const int lread = lane * 8;
  const int arow = (wm >> 4);                          // 0 or 8
  const int brow = (wn >> 4);                          // 0,4,8,12
  for (int kt = 0; kt < 17; ++kt) {
    const int cur = kt & 1;
    const half_t* SA_h = sm + cur * 32768;
    const half_t* SA_l = SA_h + 8192;
    const half_t* SB_h = SA_h + 16384;
    const half_t* SB_l = SA_h + 24576;
    const bool pre = kt < 16;
    f16x8 ah[4], al[4], bh0[2], bl0[2], bh1[2], bl1[2];

    // ---- phase A: quadrant (0,0); stage q0 for next step ----
#pragma unroll
    for (int i = 0; i < 4; ++i) {
      ah[i] = *(const f16x8*)(SA_h + (arow + i) * 512 + lread);
      al[i] = *(const f16x8*)(SA_l + (arow + i) * 512 + lread);
    }
#pragma unroll
    for (int j = 0; j < 2; ++j) {
      bh0[j] = *(const f16x8*)(SB_h + (brow + j) * 512 + lread);
      bl0[j] = *(const f16x8*)(SB_l + (brow + j) * 512 + lread);
    }
    if (pre) stage(cur ^ 1, kt + 1, 0);
    __builtin_amdgcn_s_barrier();
    asm volatile("s_waitcnt lgkmcnt(0)" ::: "memory");
    __builtin_amdgcn_sched_barrier(0);
    __builtin_amdgcn_s_setprio(1);
#pragma unroll
    for (int i = 0; i < 4; ++i)
#pragma unroll
      for (int j = 0; j < 2; ++j) {
        acc[i][j] = __builtin_amdgcn_mfma_f32_16x16x32_f16(ah[i], bh0[j], acc[i][j], 0, 0, 0);
        acc[i][j] = __builtin_amdgcn_mfma_f32_16x16x32_f16(ah[i], bl0[j], acc[i][j], 0, 0, 0);
        acc[i][j] = __builtin_amdgcn_mfma_f32_16x16x32_f16(al[i], bh0[j], acc[i][j], 0, 0, 0);
      }
    __builtin_amdgcn_s_setprio(0);
    __builtin_amdgcn_s_barrier();

    // ---- phase B: quadrant (0,1); reuse a, load b1; stage q1 ----
#pragma unroll
    for (int j = 0; j < 2; ++j) {
      bh1[j] = *(const f16x8*)(SB_h + (brow + 2 + j) * 512 + lread);
      bl1[j] = *(const f16x8*)(SB_l + (brow + 2 + j) * 512 + lread);
    }
    if (pre) stage(cur ^ 1, kt + 1, 1);
    __builtin_amdgcn_s_barrier();
    asm volatile("s_waitcnt lgkmcnt(0)" ::: "memory");
    __builtin_amdgcn_sched_barrier(0);
    __builtin_amdgcn_s_setprio(1);
#pragma unroll
    for (int i = 0; i < 4; ++i)
#pragma unroll
      for (int j = 0; j < 2; ++j) {
        acc[i][2 + j] = __builtin_amdgcn_mfma_f32_16x16x32_f16(ah[i], bh1[j], acc[i][2 + j], 0, 0, 0);
        acc[i][2 + j] = __builtin_amdgcn_mfma_f32_16x16x32_f16(ah[i], bl1[j], acc[i][2 + j], 0, 0, 0);
        acc[i][2 + j] = __builtin_amdgcn_mfma_f32_16x16x32_f16(al[i], bh1[j], acc[i][2 + j], 0, 0, 0);
      }
    __builtin_amdgcn_s_setprio(0);
    __builtin_amdgcn_s_barrier();

    // ---- phase C: quadrants (1,1)+(1,0); load a rows 4..7, reuse b1/b0 ----
#pragma unroll
    for (int i = 0; i < 4; ++i) {
      ah[i] = *(const f16x8*)(SA_h + (arow + 4 + i) * 512 + lread);
      al[i] = *(const f16x8*)(SA_l + (arow + 4 + i) * 512 + lread);
    }
    __builtin_amdgcn_s_barrier();
    asm volatile("s_waitcnt lgkmcnt(0)" ::: "memory");
    __builtin_amdgcn_sched_barrier(0);
    __builtin_amdgcn_s_setprio(1);
#pragma unroll
    for (int i = 0; i < 4; ++i)
#pragma unroll
      for (int j = 0; j < 2; ++j) {
        acc[4 + i][2 + j] = __builtin_amdgcn_mfma_f32_16x16x32_f16(ah[i], bh1[j], acc[4 + i][2 + j], 0, 0, 0);
        acc[4 + i][2 + j] = __builtin_amdgcn_mfma_f32_16x16x32_f16(ah[i], bl1[j], acc[4 + i][2 + j], 0, 0, 0);
        acc[4 + i][2 + j] = __builtin_amdgcn_mfma_f32_16x16x32_f16(al[i], bh1[j], acc[4 + i][2 + j], 0, 0, 0);
      }
#pragma unroll
    for (int i = 0; i < 4; ++i)
#pragma unroll
      for (int j = 0; j < 2; ++j) {
        acc[4 + i][j] = __builtin_amdgcn_mfma_f32_16x16x32_f16(ah[i], bh0[j], acc[4 + i][j], 0, 0, 0);
        acc[4 + i][j] = __builtin_amdgcn_mfma_f32_16x16x32_f16(ah[i], bl0[j], acc[4 + i][j], 0, 0, 0);
        acc[4 + i][j] = __builtin_amdgcn_mfma_f32_16x16x32_f16(al[i], bh0[j], acc[4 + i][j], 0, 0, 0);
      }
    __builtin_amdgcn_s_setprio(0);
    asm volatile("s_waitcnt vmcnt(0)" ::: "memory");   // next step's buffer ready
    __builtin_amdgcn_s_barrier();
  }

  int ml = lane & 15, quad = lane >> 4;
#pragma unroll
  for (int f = 0; f < 8; ++f)
#pragma unroll
    for (int g = 0; g < 4; ++g) {
      int gm = m0 + wm + f * 16 + quad * 4;
      int gn = n0 + wn + g * 16 + ml;
      float* o = C + (size_t)gm * 8192 + gn;
#pragma unroll
      for (int rr = 0; rr < 4; ++rr)
        o[(size_t)rr * 8192] = acc[f][g][rr];
    }
}

// ---------------- host orchestration ----------------

extern "C" void kernel_launch(void* const* d_in, const int* in_sizes, int n_in,
                              void* d_out, int out_size, void* d_ws, size_t ws_size,
                              hipStream_t stream) {
  (void)in_sizes; (void)n_in; (void)out_size; (void)ws_size;
  const float* u  = (const float*)d_in[0];   // 65536
  const float* Ab = (const float*)d_in[1];   // 512x512
  const float* Bb = (const float*)d_in[2];   // 512
  const float* x0 = (const float*)d_in[3];   // 512
  float* out = (float*)d_out;                // 65536x512 fp32

  char* base = (char*)d_ws;
  size_t off = 0;
  auto carve = [&](size_t bytes) -> char* {
    char* p = base + off;
    off = (off + bytes + 255) & ~(size_t)255;
    return p;
  };
  float*  Vp  = (float*)carve(16 * MSZ * 4);             // Ab^1..Ab^16 fp32
  float*  Sp  = (float*)carve(11 * MSZ * 4);             // Ab^{16*2^l}, l=1..11
  float*  Kb  = (float*)carve((size_t)16 * 512 * 4);
  half_t* Wh  = (half_t*)carve((size_t)8192 * KPAD * 2);
  half_t* Wl  = (half_t*)carve((size_t)8192 * KPAD * 2);
  half_t* x0h = (half_t*)carve(512 * 2);
  // Overlays (stream-ordered dead-region reuse):
  size_t zoff[13]; zoff[0] = 0;
  for (int l = 0; l < 12; ++l) zoff[l + 1] = zoff[l] + (size_t)(4096 >> l) * 512;
  size_t xoff[13]; xoff[1] = 0;
  for (int l = 1; l < 12; ++l) xoff[l + 1] = xoff[l] + (size_t)(4096 >> l) * 512;
  // Z + Xpool overlay V[0..14] (dead after wcat_fill)
  half_t* Zh  = (half_t*)Vp;
  half_t* Xph = (half_t*)((char*)Vp + ((zoff[12] * 2 + 255) & ~(size_t)255));
  // Xcat pair overlays Sp (dead after down-sweep l=1)
  half_t* Xch = (half_t*)Sp;
  half_t* Xcl = (half_t*)((char*)Sp + (((size_t)4096 * KPAD * 2 + 255) & ~(size_t)255));

  // Zero chain outputs (Vp slots 1..15 + Sp, contiguous 26*MSZ fp32) for atomics
  {
    int n4 = (int)(26 * MSZ / 4);
    hipLaunchKernelGGL(zero_kernel, dim3((n4 + 255) / 256), dim3(256), 0, stream,
                       (float4*)(Vp + MSZ), n4);
  }
  hipLaunchKernelGGL(copy_ab_kernel, dim3(1024), dim3(256), 0, stream, Ab, Vp);
  hipLaunchKernelGGL(cast_x0_kernel, dim3(1), dim3(512), 0, stream, x0, x0h);

  // V-chain by doubling: V_{t+s} = V_t @ V_s, t=1..s, s=1,2,4,8 (batched, split-K)
  for (int s = 1; s <= 8; s <<= 1) {
    hipLaunchKernelGGL(gemm_nn512, dim3(8, 8, 4 * s), dim3(256), 0, stream,
                       Vp, (long)MSZ,
                       Vp + (size_t)(s - 1) * MSZ, 0L,
                       Vp + (size_t)s * MSZ, (long)MSZ);
  }
  // Squarings: S_1 = (Ab^16)^2, S_l = S_{l-1}^2
  for (int l = 1; l <= 11; ++l) {
    const float* Aop = (l == 1) ? Vp + 15 * MSZ : Sp + (size_t)(l - 2) * MSZ;
    hipLaunchKernelGGL(gemm_nn512, dim3(8, 8, 4), dim3(256), 0, stream,
                       Aop, 0L, Aop, 0L, Sp + (size_t)(l - 1) * MSZ, 0L);
  }

  hipLaunchKernelGGL(kbuild_kernel, dim3(2048), dim3(256), 0, stream, Vp, Bb, Kb);
  hipLaunchKernelGGL(wcat_fill_kernel,
                     dim3((unsigned)(((size_t)8192 * KPAD + 255) / 256)), dim3(256), 0, stream,
                     Vp, Kb, Wh, Wl);
  // From here V[0..14] is dead -> Z/Xpool overlay valid.
  hipLaunchKernelGGL(leaf_kernel, dim3(4096), dim3(512), 0, stream, u, Kb, Zh);

  auto Smat = [&](int l) -> const float* {
    return (l == 0) ? (Vp + 15 * MSZ) : (Sp + (size_t)(l - 1) * MSZ);
  };

  // Up-sweep: Z_{l+1}[j] = S_l Z_l[2j] + Z_l[2j+1]
  for (int l = 0; l <= 10; ++l) {
    int M = 1 << (11 - l);
    hipLaunchKernelGGL(gemm_nt_sweep, dim3((unsigned)((M + 63) / 64), 8), dim3(256), 0, stream,
                       Zh + zoff[l], 1024L, Smat(l),
                       Zh + zoff[l] + 512, 1024L,
                       Zh + zoff[l + 1], (half_t*)0, 512L, 1, 0, 0, M);
  }
  // Down-sweep: X_l[2j+1] = S_l X_{l+1}[j] + Z_l[2j]; X_l[2j] = X_{l+1}[j] (fused)
  for (int l = 11; l >= 0; --l) {
    int M = 1 << (11 - l);
    const half_t* Xup = (l == 11) ? x0h : Xph + xoff[l + 1];
    half_t* Ch = (l == 0) ? Xch : Xph + xoff[l];
    half_t* Cl = (l == 0) ? Xcl : (half_t*)0;
    long ldC = (l == 0) ? (long)KPAD : 512L;
    if (l == 0) {  // Sp is dead now; Xcat overlay becomes live
      hipLaunchKernelGGL(xtail_kernel, dim3(512), dim3(256), 0, stream, u, Xch, Xcl);
    }
    hipLaunchKernelGGL(gemm_nt_sweep, dim3((unsigned)((M + 63) / 64), 8), dim3(256), 0, stream,
                       Xup, 512L, Smat(l),
                       Zh + zoff[l], 1024L,
                       Ch, Cl, ldC, 2, 1, 1, M);
  }

  // Main GEMM: all 65536x512 outputs, fp32 store. 512 blocks x 512 threads.
  hipLaunchKernelGGL(gemm_main, dim3(512), dim3(512), 0, stream, Xch, Xcl, Wh, Wl, out);
}

// Round 3
// 699.003 us; speedup vs baseline: 1.3683x; 1.1677x over previous
//
#include <hip/hip_runtime.h>
#include <cstdint>
#include <cstddef>

// HiPPO x_{k+1} = Ab x_k + b u_k, f[k]=x_{k+1}, L=65536, N=512.
// Chunked scan (C=16, G=4096): one big GEMM F(4096x8192)=Xcat(4096x544)@Wcat,
// chunk states via Blelloch sweep with on-device matrix powers.
// Numerics: split-f16 (Ootomo), fp32 accumulate -> ~22-bit mantissa.
// R7: attack the serial small-kernel chain (~700us over ~44 dispatches):
//  - fuse squaring T_l = T_{l-1}^2 with up-sweep level l-1 into one launch
//    (block-partition; identical deps) -> 22 launches become 11.
//  - software-pipeline (depth-2 reg prefetch) sq_body and sweep_body so the
//    ~600-cyc global load latency hides under ds_read+mfma+barrier.
//  - fuse zero/copy/cast init kernels into one.
// gemm_main (115us, MfmaUtil 38.6%) unchanged from R6.
// Workspace ~46 MB (stay under 53 MB).

typedef _Float16 half_t;
typedef _Float16 f16x8 __attribute__((ext_vector_type(8)));
typedef float f32x4 __attribute__((ext_vector_type(4)));

static constexpr int KPAD = 544;               // 512 + 16 u-taps + 16 pad
static constexpr size_t MSZ = (size_t)512 * 512;
static constexpr float INV2048 = 1.f / 2048.f;

__device__ inline void split1(float v, half_t& h, half_t& l) {
  h = (half_t)v;
  l = (half_t)((v - (float)h) * 2048.f);
}
// residual split: l is the true residual (no 2048 scale); consumer (gemm_main)
// accumulates h*l' + l*h' directly into the same fp32 accumulator.
__device__ inline void split1r(float v, half_t& h, half_t& l) {
  h = (half_t)v;
  l = (half_t)(v - (float)h);
}

// ---------------- fused init: zero(26*MSZ fp32) + copy Ab + cast x0 ----------
__global__ void init_kernel(float4* __restrict__ zp, const float* __restrict__ Ab,
                            float* __restrict__ V0, const float* __restrict__ x0,
                            half_t* __restrict__ xh) {
  int bid = blockIdx.x, tid = threadIdx.x;
  if (bid < 6656) {                       // 26*MSZ/4 = 1703936 = 6656*256
    zp[bid * 256 + tid] = make_float4(0.f, 0.f, 0.f, 0.f);
  } else if (bid < 7680) {                // 262144 = 1024*256
    int i = (bid - 6656) * 256 + tid;
    V0[i] = Ab[i];
  } else {
    xh[tid] = (half_t)x0[tid];
    xh[tid + 256] = (half_t)x0[tid + 256];
  }
}

// K[t,n] = (Ab^t b)[n], t=0..15. One wave per (t,n): coalesced m-stride + reduce.
__global__ void kbuild_kernel(const float* __restrict__ V, const float* __restrict__ b,
                              float* __restrict__ K) {
  int gw = blockIdx.x * 4 + (threadIdx.x >> 6);   // 0..8191
  int lane = threadIdx.x & 63;
  int t = gw >> 9, n = gw & 511;
  if (t == 0) { if (lane == 0) K[n] = b[n]; return; }
  const float* row = V + (size_t)(t - 1) * MSZ + (size_t)n * 512;
  float acc = 0.f;
#pragma unroll
  for (int m = 0; m < 512; m += 64) acc += row[m + lane] * b[m + lane];
#pragma unroll
  for (int s = 32; s; s >>= 1) acc += __shfl_down(acc, s, 64);
  if (lane == 0) K[t * 512 + n] = acc;
}

// WcatT[(i*512+n), k]: k<512 -> Ab^{i+1}[n,k]; 512+j -> (j<=i)?K[i-j,n]:0; pad 0
__global__ void wcat_fill_kernel(const float* __restrict__ V, const float* __restrict__ K,
                                 half_t* __restrict__ Wh, half_t* __restrict__ Wl) {
  size_t idx = (size_t)blockIdx.x * 256 + threadIdx.x;
  if (idx >= (size_t)8192 * KPAD) return;
  int row = (int)(idx / KPAD), k = (int)(idx % KPAD);
  int i = row >> 9, n = row & 511;
  float v = 0.f;
  if (k < 512) v = V[(size_t)i * MSZ + (size_t)n * 512 + k];
  else if (k < 528) { int j = k - 512; if (j <= i) v = K[(i - j) * 512 + n]; }
  half_t h, l; split1r(v, h, l);
  Wh[idx] = h; Wl[idx] = l;
}

// Z0[c,n] = sum_{j<16} K[15-j,n] * u[16c+j]   (plain f16 out)
__global__ void leaf_kernel(const float* __restrict__ u, const float* __restrict__ K,
                            half_t* __restrict__ Z) {
  __shared__ float us[16];
  int c = blockIdx.x, n = threadIdx.x;
  if (n < 16) us[n] = u[c * 16 + n];
  __syncthreads();
  float acc = 0.f;
#pragma unroll
  for (int j = 0; j < 16; ++j) acc += K[(15 - j) * 512 + n] * us[j];
  Z[(size_t)c * 512 + n] = (half_t)acc;
}

// Xcat cols [512,544): u chunk (16 taps) + zero pad (16), split pair
__global__ void xtail_kernel(const float* __restrict__ u,
                             half_t* __restrict__ Xh, half_t* __restrict__ Xl) {
  int idx = blockIdx.x * 256 + threadIdx.x;    // 4096*32
  int c = idx >> 5, j = idx & 31;
  float v = (j < 16) ? u[c * 16 + j] : 0.f;
  size_t o = (size_t)c * KPAD + 512 + j;
  half_t h, l; split1r(v, h, l);
  Xh[o] = h; Xl[o] = l;
}

// -------- chain GEMM body: C += A(512x512 fp32) @ B(512x512 fp32) ------------
// split-on-the-fly, fragment-native LDS, one split-K=4 slice (sl), 64x64 tile.
// Depth-2 register prefetch: global loads for kt+1 issue under kt's mfma.
__device__ __forceinline__ void sq_body(
    const float* __restrict__ A, const float* __restrict__ B, float* __restrict__ C,
    int bx, int by, int sl,
    half_t* __restrict__ Ash, half_t* __restrict__ Asl,
    half_t* __restrict__ Bsh, half_t* __restrict__ Bsl) {
  int m0 = bx * 64, n0 = by * 64;
  int tid = threadIdx.x, wave = tid >> 6, lane = tid & 63;
  int wm = (wave & 1) * 32, wn = (wave >> 1) * 32;
  f32x4 acc[2][2], accc[2][2];
#pragma unroll
  for (int i = 0; i < 2; ++i)
#pragma unroll
    for (int j = 0; j < 2; ++j) {
      acc[i][j] = (f32x4){0.f, 0.f, 0.f, 0.f};
      accc[i][j] = (f32x4){0.f, 0.f, 0.f, 0.f};
    }
  int rb = tid >> 6, mm = tid & 15, kseg = (tid >> 4) & 3;
  const float* ar = A + (size_t)(m0 + rb * 16 + mm) * 512 + sl * 128 + kseg * 8;
  const float* bc = B + (size_t)(sl * 128 + kseg * 8) * 512 + n0 + rb * 16 + mm;
  float4 a0 = *(const float4*)ar, a1 = *(const float4*)(ar + 4);
  float bv[8];
#pragma unroll
  for (int j = 0; j < 8; ++j) bv[j] = bc[(size_t)j * 512];
#pragma unroll
  for (int kt = 0; kt < 4; ++kt) {
    {
      float aa[8] = {a0.x, a0.y, a0.z, a0.w, a1.x, a1.y, a1.z, a1.w};
      f16x8 hv, lv;
#pragma unroll
      for (int j = 0; j < 8; ++j) { half_t h, l; split1(aa[j], h, l); hv[j] = h; lv[j] = l; }
      *(f16x8*)(Ash + tid * 8) = hv;
      *(f16x8*)(Asl + tid * 8) = lv;
#pragma unroll
      for (int j = 0; j < 8; ++j) { half_t h, l; split1(bv[j], h, l); hv[j] = h; lv[j] = l; }
      *(f16x8*)(Bsh + tid * 8) = hv;
      *(f16x8*)(Bsl + tid * 8) = lv;
    }
    __syncthreads();
    if (kt < 3) {   // prefetch kt+1 under this kt's ds_read+mfma
      a0 = *(const float4*)(ar + (kt + 1) * 32);
      a1 = *(const float4*)(ar + (kt + 1) * 32 + 4);
#pragma unroll
      for (int j = 0; j < 8; ++j) bv[j] = bc[(size_t)((kt + 1) * 32 + j) * 512];
    }
    f16x8 afh[2], afl[2], bfh[2], bfl[2];
#pragma unroll
    for (int i = 0; i < 2; ++i) {
      int ra = (wm >> 4) + i, rbn = (wn >> 4) + i;
      afh[i] = *(const f16x8*)(Ash + ra * 512 + lane * 8);
      afl[i] = *(const f16x8*)(Asl + ra * 512 + lane * 8);
      bfh[i] = *(const f16x8*)(Bsh + rbn * 512 + lane * 8);
      bfl[i] = *(const f16x8*)(Bsl + rbn * 512 + lane * 8);
    }
#pragma unroll
    for (int i = 0; i < 2; ++i)
#pragma unroll
      for (int j = 0; j < 2; ++j) {
        acc[i][j] = __builtin_amdgcn_mfma_f32_16x16x32_f16(afh[i], bfh[j], acc[i][j], 0, 0, 0);
        accc[i][j] = __builtin_amdgcn_mfma_f32_16x16x32_f16(afh[i], bfl[j], accc[i][j], 0, 0, 0);
        accc[i][j] = __builtin_amdgcn_mfma_f32_16x16x32_f16(afl[i], bfh[j], accc[i][j], 0, 0, 0);
      }
    __syncthreads();
  }
  int ml = lane & 15, quad = lane >> 4;
  for (int i = 0; i < 2; ++i)
    for (int j = 0; j < 2; ++j)
      for (int rr = 0; rr < 4; ++rr) {
        int gm = m0 + wm + i * 16 + quad * 4 + rr;
        int gn = n0 + wn + j * 16 + ml;
        atomicAdd(&C[(size_t)gm * 512 + gn], acc[i][j][rr] + accc[i][j][rr] * INV2048);
      }
}

__global__ __launch_bounds__(256)
void gemm_nn512(const float* __restrict__ A, long sA,
                const float* __restrict__ B, long sB,
                float* __restrict__ C, long sC) {
  __shared__ __align__(16) half_t s0[64 * 32], s1[64 * 32], s2[64 * 32], s3[64 * 32];
  int bz = blockIdx.z, bb = bz >> 2, sl = bz & 3;
  sq_body(A + (size_t)bb * sA, B + (size_t)bb * sB, C + (size_t)bb * sC,
          blockIdx.x, blockIdx.y, sl, s0, s1, s2, s3);
}

// -------- sweep GEMM body: C(Mx512) = A(Mx512 f16) @ S^T + D; S fp32 ---------
// Depth-2 register prefetch; fused even-row copy (down-sweep rowcopy).
__device__ __forceinline__ void sweep_body(
    const half_t* __restrict__ A, long ldA, const float* __restrict__ BT,
    const half_t* __restrict__ D, long ldD,
    half_t* __restrict__ Ch, half_t* __restrict__ Cl, long ldC,
    int rScale, int rOff, int doCopy, int M, int bx, int by,
    half_t* __restrict__ Ash, half_t* __restrict__ Bsh, half_t* __restrict__ Bsl) {
  int m0 = bx * 64, n0 = by * 64;
  int tid = threadIdx.x, wave = tid >> 6, lane = tid & 63;
  int wm = (wave & 1) * 32, wn = (wave >> 1) * 32;
  f32x4 acc[2][2], accc[2][2];
#pragma unroll
  for (int i = 0; i < 2; ++i)
#pragma unroll
    for (int j = 0; j < 2; ++j) {
      acc[i][j] = (f32x4){0.f, 0.f, 0.f, 0.f};
      accc[i][j] = (f32x4){0.f, 0.f, 0.f, 0.f};
    }
  int rb = tid >> 6, mm = tid & 15, kseg = (tid >> 4) & 3;
  int arow = m0 + rb * 16 + mm;
  const half_t* ap = A + (size_t)arow * ldA + kseg * 8;
  const float* bp = BT + (size_t)(n0 + rb * 16 + mm) * 512 + kseg * 8;
  f16x8 av = (f16x8){0, 0, 0, 0, 0, 0, 0, 0};
  if (arow < M) av = *(const f16x8*)ap;
  float4 bv0 = *(const float4*)bp;
  float4 bv1 = *(const float4*)(bp + 4);
#pragma unroll
  for (int kt = 0; kt < 16; ++kt) {
    int k0 = kt * 32;
    *(f16x8*)(Ash + tid * 8) = av;
    // fused even-row copy: out[2*arow, k0+kseg*8 ..] = A values (down-sweep)
    if (doCopy && k0 >= n0 && k0 < n0 + 64 && arow < M) {
      size_t co = (size_t)(2 * arow) * ldC + k0 + kseg * 8;
      *(f16x8*)(Ch + co) = av;
      if (Cl) *(f16x8*)(Cl + co) = (f16x8){0, 0, 0, 0, 0, 0, 0, 0};
    }
    {
      float bb[8] = {bv0.x, bv0.y, bv0.z, bv0.w, bv1.x, bv1.y, bv1.z, bv1.w};
      f16x8 hv, lv;
#pragma unroll
      for (int j = 0; j < 8; ++j) { half_t h, l; split1(bb[j], h, l); hv[j] = h; lv[j] = l; }
      *(f16x8*)(Bsh + tid * 8) = hv;
      *(f16x8*)(Bsl + tid * 8) = lv;
    }
    __syncthreads();
    if (kt < 15) {  // prefetch kt+1 under this kt's ds_read+mfma
      if (arow < M) av = *(const f16x8*)(ap + (kt + 1) * 32);
      bv0 = *(const float4*)(bp + (kt + 1) * 32);
      bv1 = *(const float4*)(bp + (kt + 1) * 32 + 4);
    }
    f16x8 af[2], bfh[2], bfl[2];
#pragma unroll
    for (int i = 0; i < 2; ++i) {
      af[i] = *(const f16x8*)(Ash + ((wm >> 4) + i) * 512 + lane * 8);
      bfh[i] = *(const f16x8*)(Bsh + ((wn >> 4) + i) * 512 + lane * 8);
      bfl[i] = *(const f16x8*)(Bsl + ((wn >> 4) + i) * 512 + lane * 8);
    }
#pragma unroll
    for (int i = 0; i < 2; ++i)
#pragma unroll
      for (int j = 0; j < 2; ++j) {
        acc[i][j] = __builtin_amdgcn_mfma_f32_16x16x32_f16(af[i], bfh[j], acc[i][j], 0, 0, 0);
        accc[i][j] = __builtin_amdgcn_mfma_f32_16x16x32_f16(af[i], bfl[j], accc[i][j], 0, 0, 0);
      }
    __syncthreads();
  }
  int ml = lane & 15, quad = lane >> 4;
  for (int i = 0; i < 2; ++i)
    for (int j = 0; j < 2; ++j)
      for (int rr = 0; rr < 4; ++rr) {
        int gm = m0 + wm + i * 16 + quad * 4 + rr;
        int gn = n0 + wn + j * 16 + ml;
        if (gm >= M) continue;
        float v = acc[i][j][rr] + accc[i][j][rr] * INV2048;
        if (D) v += (float)D[(size_t)gm * ldD + gn];
        size_t co = ((size_t)gm * rScale + rOff) * ldC + gn;
        if (Cl) { half_t h, l; split1r(v, h, l); Ch[co] = h; Cl[co] = l; }
        else Ch[co] = (half_t)v;
      }
}

__global__ __launch_bounds__(256)
void gemm_nt_sweep(const half_t* __restrict__ A, long ldA,
                   const float* __restrict__ BT,
                   const half_t* __restrict__ D, long ldD,
                   half_t* __restrict__ Ch, half_t* __restrict__ Cl,
                   long ldC, int rScale, int rOff, int doCopy, int M) {
  __shared__ __align__(16) half_t s0[64 * 32], s1[64 * 32], s2[64 * 32];
  sweep_body(A, ldA, BT, D, ldD, Ch, Cl, ldC, rScale, rOff, doCopy, M,
             blockIdx.x, blockIdx.y, s0, s1, s2);
}

// -------- fused: squaring T_l = T_{l-1}^2 (blocks 0..255, split-K=4) ---------
//          + up-sweep level l-1: Zout[j] = T_{l-1} Zin[2j] + Zin[2j+1] --------
// Both roles read T_{l-1} (L2-friendly); disjoint outputs; no inter-role dep.
__global__ __launch_bounds__(256)
void fused_up(const float* __restrict__ T, float* __restrict__ Tout,
              const half_t* __restrict__ Zin, half_t* __restrict__ Zout, int M) {
  __shared__ __align__(16) half_t s0[64 * 32], s1[64 * 32], s2[64 * 32], s3[64 * 32];
  int bid = blockIdx.x;
  if (bid < 256) {
    sq_body(T, T, Tout, bid & 7, (bid >> 3) & 7, bid >> 6, s0, s1, s2, s3);
  } else {
    int b = bid - 256;
    sweep_body(Zin, 1024L, T, Zin + 512, 1024L, Zout, (half_t*)0, 512L,
               1, 0, 0, M, b >> 3, b & 7, s0, s1, s2);
  }
}

// -------- main GEMM: 4096 x 8192 x 544 --------------------------------------
__device__ inline void load_lds16(const half_t* g, half_t* l) {
  __builtin_amdgcn_global_load_lds(
      (const __attribute__((address_space(1))) uint32_t*)g,
      (__attribute__((address_space(3))) uint32_t*)l, 16, 0, 0);
}

// 256x256 tile, BK=32 (17 steps), 8 waves (2Mx4N), wave tile 128x64.
// LDS: 2 buffers x 4 streams (Ah,Al,Bh,Bl) x 256x32 f16 = 128 KiB, dbuf.
// 3 phases per K-step; vmcnt drained once per step. Residual split -> single
// fp32 accumulator. Unchanged from R6 (115us, MfmaUtil 38.6%).
__global__ __launch_bounds__(512, 2)
void gemm_main(const half_t* __restrict__ Ah, const half_t* __restrict__ Al,
               const half_t* __restrict__ Bh, const half_t* __restrict__ Bl,
               float* __restrict__ C) {
  __shared__ __align__(16) half_t sm[2 * 4 * 8192];   // 128 KiB
  int bid = blockIdx.x;
  int xcd = bid & 7, loc = bid >> 3;                  // loc 0..63
  int mt = (xcd & 1) * 8 + (loc >> 3);                // 0..15
  int nt = (xcd >> 1) * 8 + (loc & 7);                // 0..31
  int m0 = mt * 256, n0 = nt * 256;
  int tid = threadIdx.x, wave = tid >> 6, lane = tid & 63;
  int wm = (wave & 1) * 128, wn = (wave >> 1) * 64;
  int mm = lane & 15, kseg = lane >> 4;
  f32x4 acc[8][4];
#pragma unroll
  for (int f = 0; f < 8; ++f)
#pragma unroll
    for (int g = 0; g < 4; ++g) acc[f][g] = (f32x4){0.f, 0.f, 0.f, 0.f};

  const size_t ga0 = (size_t)(m0 + wave * 16 + mm) * KPAD + kseg * 8;
  const size_t gb0 = (size_t)(n0 + wave * 16 + mm) * KPAD + kseg * 8;
  const size_t qstep = (size_t)128 * KPAD;            // q=1: +128 rows

  auto stage = [&](int nb, int kt, int q) {
    size_t go = (size_t)kt * 32 + (size_t)q * qstep;
    half_t* d = sm + (size_t)nb * 32768 + (size_t)(wave + 8 * q) * 512;
    load_lds16(Ah + ga0 + go, d);
    load_lds16(Al + ga0 + go, d + 8192);
    load_lds16(Bh + gb0 + go, d + 16384);
    load_lds16(Bl + gb0 + go, d + 24576);
  };

  stage(0, 0, 0);
  stage(0, 0, 1);
  asm volatile("s_waitcnt vmcnt(0)" ::: "memory");
  __builtin_amdgcn_s_barrier();

  const int lread = lane * 8;
  const int arow = (wm >> 4);                          // 0 or 8
  const int brow = (wn >> 4);                          // 0,4,8,12
  for (int kt = 0; kt < 17; ++kt) {
    const int cur = kt & 1;
    const half_t* SA_h = sm + cur * 32768;
    const half_t* SA_l = SA_h + 8192;
    const half_t* SB_h = SA_h + 16384;
    const half_t* SB_l = SA_h + 24576;
    const bool pre = kt < 16;
    f16x8 ah[4], al[4], bh0[2], bl0[2], bh1[2], bl1[2];

    // ---- phase A: quadrant (0,0); stage q0 for next step ----
#pragma unroll
    for (int i = 0; i < 4; ++i) {
      ah[i] = *(const f16x8*)(SA_h + (arow + i) * 512 + lread);
      al[i] = *(const f16x8*)(SA_l + (arow + i) * 512 + lread);
    }
#pragma unroll
    for (int j = 0; j < 2; ++j) {
      bh0[j] = *(const f16x8*)(SB_h + (brow + j) * 512 + lread);
      bl0[j] = *(const f16x8*)(SB_l + (brow + j) * 512 + lread);
    }
    if (pre) stage(cur ^ 1, kt + 1, 0);
    __builtin_amdgcn_s_barrier();
    asm volatile("s_waitcnt lgkmcnt(0)" ::: "memory");
    __builtin_amdgcn_sched_barrier(0);
    __builtin_amdgcn_s_setprio(1);
#pragma unroll
    for (int i = 0; i < 4; ++i)
#pragma unroll
      for (int j = 0; j < 2; ++j) {
        acc[i][j] = __builtin_amdgcn_mfma_f32_16x16x32_f16(ah[i], bh0[j], acc[i][j], 0, 0, 0);
        acc[i][j] = __builtin_amdgcn_mfma_f32_16x16x32_f16(ah[i], bl0[j], acc[i][j], 0, 0, 0);
        acc[i][j] = __builtin_amdgcn_mfma_f32_16x16x32_f16(al[i], bh0[j], acc[i][j], 0, 0, 0);
      }
    __builtin_amdgcn_s_setprio(0);
    __builtin_amdgcn_s_barrier();

    // ---- phase B: quadrant (0,1); reuse a, load b1; stage q1 ----
#pragma unroll
    for (int j = 0; j < 2; ++j) {
      bh1[j] = *(const f16x8*)(SB_h + (brow + 2 + j) * 512 + lread);
      bl1[j] = *(const f16x8*)(SB_l + (brow + 2 + j) * 512 + lread);
    }
    if (pre) stage(cur ^ 1, kt + 1, 1);
    __builtin_amdgcn_s_barrier();
    asm volatile("s_waitcnt lgkmcnt(0)" ::: "memory");
    __builtin_amdgcn_sched_barrier(0);
    __builtin_amdgcn_s_setprio(1);
#pragma unroll
    for (int i = 0; i < 4; ++i)
#pragma unroll
      for (int j = 0; j < 2; ++j) {
        acc[i][2 + j] = __builtin_amdgcn_mfma_f32_16x16x32_f16(ah[i], bh1[j], acc[i][2 + j], 0, 0, 0);
        acc[i][2 + j] = __builtin_amdgcn_mfma_f32_16x16x32_f16(ah[i], bl1[j], acc[i][2 + j], 0, 0, 0);
        acc[i][2 + j] = __builtin_amdgcn_mfma_f32_16x16x32_f16(al[i], bh1[j], acc[i][2 + j], 0, 0, 0);
      }
    __builtin_amdgcn_s_setprio(0);
    __builtin_amdgcn_s_barrier();

    // ---- phase C: quadrants (1,1)+(1,0); load a rows 4..7, reuse b1/b0 ----
#pragma unroll
    for (int i = 0; i < 4; ++i) {
      ah[i] = *(const f16x8*)(SA_h + (arow + 4 + i) * 512 + lread);
      al[i] = *(const f16x8*)(SA_l + (arow + 4 + i) * 512 + lread);
    }
    __builtin_amdgcn_s_barrier();
    asm volatile("s_waitcnt lgkmcnt(0)" ::: "memory");
    __builtin_amdgcn_sched_barrier(0);
    __builtin_amdgcn_s_setprio(1);
#pragma unroll
    for (int i = 0; i < 4; ++i)
#pragma unroll
      for (int j = 0; j < 2; ++j) {
        acc[4 + i][2 + j] = __builtin_amdgcn_mfma_f32_16x16x32_f16(ah[i], bh1[j], acc[4 + i][2 + j], 0, 0, 0);
        acc[4 + i][2 + j] = __builtin_amdgcn_mfma_f32_16x16x32_f16(ah[i], bl1[j], acc[4 + i][2 + j], 0, 0, 0);
        acc[4 + i][2 + j] = __builtin_amdgcn_mfma_f32_16x16x32_f16(al[i], bh1[j], acc[4 + i][2 + j], 0, 0, 0);
      }
#pragma unroll
    for (int i = 0; i < 4; ++i)
#pragma unroll
      for (int j = 0; j < 2; ++j) {
        acc[4 + i][j] = __builtin_amdgcn_mfma_f32_16x16x32_f16(ah[i], bh0[j], acc[4 + i][j], 0, 0, 0);
        acc[4 + i][j] = __builtin_amdgcn_mfma_f32_16x16x32_f16(ah[i], bl0[j], acc[4 + i][j], 0, 0, 0);
        acc[4 + i][j] = __builtin_amdgcn_mfma_f32_16x16x32_f16(al[i], bh0[j], acc[4 + i][j], 0, 0, 0);
      }
    __builtin_amdgcn_s_setprio(0);
    asm volatile("s_waitcnt vmcnt(0)" ::: "memory");   // next step's buffer ready
    __builtin_amdgcn_s_barrier();
  }

  int ml = lane & 15, quad = lane >> 4;
#pragma unroll
  for (int f = 0; f < 8; ++f)
#pragma unroll
    for (int g = 0; g < 4; ++g) {
      int gm = m0 + wm + f * 16 + quad * 4;
      int gn = n0 + wn + g * 16 + ml;
      float* o = C + (size_t)gm * 8192 + gn;
#pragma unroll
      for (int rr = 0; rr < 4; ++rr)
        o[(size_t)rr * 8192] = acc[f][g][rr];
    }
}

// ---------------- host orchestration ----------------

extern "C" void kernel_launch(void* const* d_in, const int* in_sizes, int n_in,
                              void* d_out, int out_size, void* d_ws, size_t ws_size,
                              hipStream_t stream) {
  (void)in_sizes; (void)n_in; (void)out_size; (void)ws_size;
  const float* u  = (const float*)d_in[0];   // 65536
  const float* Ab = (const float*)d_in[1];   // 512x512
  const float* Bb = (const float*)d_in[2];   // 512
  const float* x0 = (const float*)d_in[3];   // 512
  float* out = (float*)d_out;                // 65536x512 fp32

  char* base = (char*)d_ws;
  size_t off = 0;
  auto carve = [&](size_t bytes) -> char* {
    char* p = base + off;
    off = (off + bytes + 255) & ~(size_t)255;
    return p;
  };
  float*  Vp  = (float*)carve(16 * MSZ * 4);             // Ab^1..Ab^16 fp32
  float*  Sp  = (float*)carve(11 * MSZ * 4);             // Ab^{16*2^l}, l=1..11
  float*  Kb  = (float*)carve((size_t)16 * 512 * 4);
  half_t* Wh  = (half_t*)carve((size_t)8192 * KPAD * 2);
  half_t* Wl  = (half_t*)carve((size_t)8192 * KPAD * 2);
  half_t* x0h = (half_t*)carve(512 * 2);
  // Overlays (stream-ordered dead-region reuse):
  size_t zoff[13]; zoff[0] = 0;
  for (int l = 0; l < 12; ++l) zoff[l + 1] = zoff[l] + (size_t)(4096 >> l) * 512;
  size_t xoff[13]; xoff[1] = 0;
  for (int l = 1; l < 12; ++l) xoff[l + 1] = xoff[l] + (size_t)(4096 >> l) * 512;
  // Z + Xpool overlay V[0..14] (dead after wcat_fill)
  half_t* Zh  = (half_t*)Vp;
  half_t* Xph = (half_t*)((char*)Vp + ((zoff[12] * 2 + 255) & ~(size_t)255));
  // Xcat pair overlays Sp (dead after down-sweep l=1)
  half_t* Xch = (half_t*)Sp;
  half_t* Xcl = (half_t*)((char*)Sp + (((size_t)4096 * KPAD * 2 + 255) & ~(size_t)255));

  // Fused init: zero chain outputs (V[1..15]+Sp for atomics) + copy Ab + cast x0
  hipLaunchKernelGGL(init_kernel, dim3(7681), dim3(256), 0, stream,
                     (float4*)(Vp + MSZ), Ab, Vp, x0, x0h);

  // V-chain by doubling: V_{t+s} = V_t @ V_s, t=1..s, s=1,2,4,8 (batched, split-K)
  for (int s = 1; s <= 8; s <<= 1) {
    hipLaunchKernelGGL(gemm_nn512, dim3(8, 8, 4 * s), dim3(256), 0, stream,
                       Vp, (long)MSZ,
                       Vp + (size_t)(s - 1) * MSZ, 0L,
                       Vp + (size_t)s * MSZ, (long)MSZ);
  }

  hipLaunchKernelGGL(kbuild_kernel, dim3(2048), dim3(256), 0, stream, Vp, Bb, Kb);
  hipLaunchKernelGGL(wcat_fill_kernel,
                     dim3((unsigned)(((size_t)8192 * KPAD + 255) / 256)), dim3(256), 0, stream,
                     Vp, Kb, Wh, Wl);
  // From here V[0..14] is dead -> Z/Xpool overlay valid.
  hipLaunchKernelGGL(leaf_kernel, dim3(4096), dim3(512), 0, stream, u, Kb, Zh);

  auto Smat = [&](int l) -> const float* {
    return (l == 0) ? (Vp + 15 * MSZ) : (Sp + (size_t)(l - 1) * MSZ);
  };

  // Fused phase FL_l (l=1..11): squaring T_l = T_{l-1}^2  AND  up-sweep level
  // l-1 (Z_l[j] = T_{l-1} Z_{l-1}[2j] + Z_{l-1}[2j+1]); both only need T_{l-1}.
  for (int l = 1; l <= 11; ++l) {
    const float* T = (l == 1) ? Vp + 15 * MSZ : Sp + (size_t)(l - 2) * MSZ;
    float* Tout = Sp + (size_t)(l - 1) * MSZ;
    int Mup = 1 << (12 - l);
    int nswp = ((Mup + 63) / 64) * 8;
    hipLaunchKernelGGL(fused_up, dim3(256 + nswp), dim3(256), 0, stream,
                       T, Tout, Zh + zoff[l - 1], Zh + zoff[l], Mup);
  }

  // Down-sweep: X_l[2j+1] = S_l X_{l+1}[j] + Z_l[2j]; X_l[2j] = X_{l+1}[j] (fused)
  for (int l = 11; l >= 0; --l) {
    int M = 1 << (11 - l);
    const half_t* Xup = (l == 11) ? x0h : Xph + xoff[l + 1];
    half_t* Ch = (l == 0) ? Xch : Xph + xoff[l];
    half_t* Cl = (l == 0) ? Xcl : (half_t*)0;
    long ldC = (l == 0) ? (long)KPAD : 512L;
    if (l == 0) {  // Sp is dead now; Xcat overlay becomes live
      hipLaunchKernelGGL(xtail_kernel, dim3(512), dim3(256), 0, stream, u, Xch, Xcl);
    }
    hipLaunchKernelGGL(gemm_nt_sweep, dim3((unsigned)((M + 63) / 64), 8), dim3(256), 0, stream,
                       Xup, 512L, Smat(l),
                       Zh + zoff[l], 1024L,
                       Ch, Cl, ldC, 2, 1, 1, M);
  }

  // Main GEMM: all 65536x512 outputs, fp32 store. 512 blocks x 512 threads.
  hipLaunchKernelGGL(gemm_main, dim3(512), dim3(512), 0, stream, Xch, Xcl, Wh, Wl, out);
}